// Round 1
// baseline (2457.406 us; speedup 1.0000x reference)
//
#include <hip/hip_runtime.h>
#include <hip/hip_bf16.h>

#define TT   128
#define BATCH 1024
#define INDIM 512
#define HIDD  1024
#define NCLS  10

typedef __bf16 bf16x8 __attribute__((ext_vector_type(8)));
typedef float  f32x4  __attribute__((ext_vector_type(4)));
typedef unsigned short u16x8 __attribute__((ext_vector_type(8)));

__device__ __forceinline__ unsigned short bf16b(float f) {
    __hip_bfloat16 h = __float2bfloat16(f);
    return __builtin_bit_cast(unsigned short, h);
}

__device__ __forceinline__ float tanh_fast(float x) {
    // tanh(x) = 1 - 2/(exp(2x)+1); graceful at +-inf (exp->inf => 1, exp->0 => -1)
    float e = __expf(2.0f * x);
    return 1.0f - 2.0f * __builtin_amdgcn_rcpf(e + 1.0f);
}

// ---------------------------------------------------------------------------
// Prep: W -> transposed bf16 hi/lo pairs.  WT[n][k] = W[k][n];
// W ~= hi + lo with hi = bf16(W), lo = bf16(W - hi)  (~2^-18 rel residual).
// Blocks 0..255: Whh (1024x1024). Blocks 256..383: Wxh (512x1024).
// ---------------------------------------------------------------------------
__global__ __launch_bounds__(256) void prep_kernel(
    const float* __restrict__ Whh, const float* __restrict__ Wxh,
    __hip_bfloat16* __restrict__ WhhT_hi, __hip_bfloat16* __restrict__ WhhT_lo,
    __hip_bfloat16* __restrict__ WxhT_hi, __hip_bfloat16* __restrict__ WxhT_lo)
{
    __shared__ float tl[64][68];   // 68: keeps float4 rows 16B-aligned, breaks bank stride
    int bid = blockIdx.x, tid = threadIdx.x;
    const float* src; int N, k0, n0, dstride;
    __hip_bfloat16 *dhi, *dlo;
    if (bid < 256) { src = Whh; N = 1024; k0 = (bid >> 4) << 6; n0 = (bid & 15) << 6;
                     dhi = WhhT_hi; dlo = WhhT_lo; dstride = 1024; }
    else { int b = bid - 256; src = Wxh; N = 1024; k0 = (b >> 4) << 6; n0 = (b & 15) << 6;
           dhi = WxhT_hi; dlo = WxhT_lo; dstride = 512; }

    int r = tid >> 2, c0 = (tid & 3) << 4;
    const float* s = src + (size_t)(k0 + r) * N + n0 + c0;
#pragma unroll
    for (int j = 0; j < 4; ++j)
        *(float4*)&tl[r][c0 + j * 4] = *(const float4*)(s + j * 4);
    __syncthreads();

    int rn = tid >> 2, ck0 = (tid & 3) << 4;
    u16x8 hi0, hi1, lo0, lo1;
#pragma unroll
    for (int j = 0; j < 16; ++j) {
        float w = tl[ck0 + j][rn];
        unsigned short hb = bf16b(w);
        float hf = __bfloat162float(__builtin_bit_cast(__hip_bfloat16, hb));
        unsigned short lb = bf16b(w - hf);
        if (j < 8) { hi0[j] = hb; lo0[j] = lb; }
        else       { hi1[j - 8] = hb; lo1[j - 8] = lb; }
    }
    size_t o = (size_t)(n0 + rn) * dstride + k0 + ck0;
    *(u16x8*)(void*)(dhi + o)     = hi0;
    *(u16x8*)(void*)(dhi + o + 8) = hi1;
    *(u16x8*)(void*)(dlo + o)     = lo0;
    *(u16x8*)(void*)(dlo + o + 8) = lo1;
}

// ---------------------------------------------------------------------------
// Convert x[:, t, :] (f32) -> bf16 staging buffer [1024][512] (b-major).
// ---------------------------------------------------------------------------
__global__ __launch_bounds__(256) void convx_kernel(
    const float* __restrict__ x, __hip_bfloat16* __restrict__ xs, int t)
{
    int bid = blockIdx.x, tid = threadIdx.x;
    int row = (bid << 2) + (tid >> 6);
    int i   = (tid & 63) << 3;
    const float* s = x + (size_t)row * (TT * INDIM) + (size_t)t * INDIM + i;
    float4 a = *(const float4*)s, b = *(const float4*)(s + 4);
    u16x8 o;
    o[0]=bf16b(a.x); o[1]=bf16b(a.y); o[2]=bf16b(a.z); o[3]=bf16b(a.w);
    o[4]=bf16b(b.x); o[5]=bf16b(b.y); o[6]=bf16b(b.z); o[7]=bf16b(b.w);
    *(u16x8*)(void*)(xs + (size_t)row * INDIM + i) = o;
}

// ---------------------------------------------------------------------------
// One recurrent step: h_next = tanh(x_t@Wxh + b_xh + h_prev@Whh + b_hh)
// Fused K = 1024 (h-part) + 512 (x-part), weights as hi/lo bf16 pairs (2-pass).
// 64x64 tile per block, grid 16x16 = 256 blocks, 4 waves, mfma 16x16x32 bf16.
// LDS: data chunk (row, c16) stored at slot (row, c16 ^ (row&7))  [XOR swizzle,
// applied on the *global source* address since global_load_lds dest is linear].
// ---------------------------------------------------------------------------
__device__ __forceinline__ void stage_tile(const __hip_bfloat16* src, int stride,
                                           char* ldsbase, int tid)
{
#pragma unroll
    for (int i = 0; i < 2; ++i) {
        int r  = (i << 5) + (tid >> 3);
        int cb = (tid & 7) ^ (r & 7);            // inverse-swizzled source chunk
        const void* g = (const void*)(src + r * stride + (cb << 3));
        void* l = (void*)(ldsbase + ((tid & 192) << 4) + (i << 12)); // wave-uniform base
        __builtin_amdgcn_global_load_lds((const __attribute__((address_space(1))) void*)g,
                                         (__attribute__((address_space(3))) void*)l,
                                         16, 0, 0);
    }
}

__device__ __forceinline__ bf16x8 frag(const char* tile, int row, int cb)
{
    return *(const bf16x8*)(tile + (row << 7) + ((cb ^ (row & 7)) << 4));
}

__global__ __launch_bounds__(256, 1) void step_kernel(
    const __hip_bfloat16* __restrict__ h_prev, __hip_bfloat16* __restrict__ h_next,
    const __hip_bfloat16* __restrict__ xs_cur, __hip_bfloat16* __restrict__ xs_next,
    const __hip_bfloat16* __restrict__ WhhT_hi, const __hip_bfloat16* __restrict__ WhhT_lo,
    const __hip_bfloat16* __restrict__ WxhT_hi, const __hip_bfloat16* __restrict__ WxhT_lo,
    const float* __restrict__ x, const float* __restrict__ b_xh, const float* __restrict__ b_hh,
    int t, int first, int last)
{
    __shared__ char smem[49152];                 // 2 bufs x (A + Bhi + Blo) x 8KB
    int tid  = threadIdx.x;
    int bx   = blockIdx.x, by = blockIdx.y;
    int bx64 = bx << 6, by64 = by << 6;
    int lane = tid & 63, wave = tid >> 6;
    int wm32 = (wave >> 1) << 5, wn32 = (wave & 1) << 5;

    // Early-issue the next-slice x loads; latency hides under the GEMM.
    int cbid = (by << 4) + bx;
    int crow = (cbid << 2) + wave;
    int ci   = lane << 3;
    float4 cv0, cv1;
    if (!last) {
        const float* cs = x + (size_t)crow * (TT * INDIM) + (size_t)(t + 1) * INDIM + ci;
        cv0 = *(const float4*)cs; cv1 = *(const float4*)(cs + 4);
    }

    f32x4 acc00 = {0,0,0,0}, acc01 = {0,0,0,0}, acc10 = {0,0,0,0}, acc11 = {0,0,0,0};

    int c0 = first ? 16 : 0;                     // step 0: h == 0, skip h-part chunks

    auto stage_chunk = [&](char* buf, int c) {
        const __hip_bfloat16 *as, *bh, *bl; int ast, bst;
        if (c < 16) {
            as = h_prev  + (size_t)by64 * HIDD + (c << 6); ast = HIDD;
            bh = WhhT_hi + (size_t)bx64 * HIDD + (c << 6);
            bl = WhhT_lo + (size_t)bx64 * HIDD + (c << 6); bst = HIDD;
        } else {
            int cc = c - 16;
            as = xs_cur  + (size_t)by64 * INDIM + (cc << 6); ast = INDIM;
            bh = WxhT_hi + (size_t)bx64 * INDIM + (cc << 6);
            bl = WxhT_lo + (size_t)bx64 * INDIM + (cc << 6); bst = INDIM;
        }
        stage_tile(as, ast, buf,         tid);
        stage_tile(bh, bst, buf + 8192,  tid);
        stage_tile(bl, bst, buf + 16384, tid);
    };

    stage_chunk(smem, c0);
    __syncthreads();

    for (int c = c0; c < 24; ++c) {
        int pb = (c - c0) & 1;
        char* cur = smem + pb * 24576;
        if (c < 23) stage_chunk(smem + (pb ^ 1) * 24576, c + 1);
        const char* At = cur;
        const char* Bh = cur + 8192;
        const char* Bl = cur + 16384;
#pragma unroll
        for (int ks = 0; ks < 2; ++ks) {
            int ar = lane & 15, kg = (ks << 2) + (lane >> 4);
            bf16x8 a0  = frag(At, wm32 + ar,       kg);
            bf16x8 a1  = frag(At, wm32 + 16 + ar,  kg);
            bf16x8 bh0 = frag(Bh, wn32 + ar,       kg);
            bf16x8 bh1 = frag(Bh, wn32 + 16 + ar,  kg);
            bf16x8 bl0 = frag(Bl, wn32 + ar,       kg);
            bf16x8 bl1 = frag(Bl, wn32 + 16 + ar,  kg);
            acc00 = __builtin_amdgcn_mfma_f32_16x16x32_bf16(a0, bh0, acc00, 0, 0, 0);
            acc00 = __builtin_amdgcn_mfma_f32_16x16x32_bf16(a0, bl0, acc00, 0, 0, 0);
            acc01 = __builtin_amdgcn_mfma_f32_16x16x32_bf16(a0, bh1, acc01, 0, 0, 0);
            acc01 = __builtin_amdgcn_mfma_f32_16x16x32_bf16(a0, bl1, acc01, 0, 0, 0);
            acc10 = __builtin_amdgcn_mfma_f32_16x16x32_bf16(a1, bh0, acc10, 0, 0, 0);
            acc10 = __builtin_amdgcn_mfma_f32_16x16x32_bf16(a1, bl0, acc10, 0, 0, 0);
            acc11 = __builtin_amdgcn_mfma_f32_16x16x32_bf16(a1, bh1, acc11, 0, 0, 0);
            acc11 = __builtin_amdgcn_mfma_f32_16x16x32_bf16(a1, bl1, acc11, 0, 0, 0);
        }
        __syncthreads();
    }

    // Epilogue: + biases, tanh, store bf16.  D layout: col=lane&15, row=(lane>>4)*4+j.
    int colb = bx64 + wn32 + (lane & 15);
    int rowb = by64 + wm32 + ((lane >> 4) << 2);
#pragma unroll
    for (int mf = 0; mf < 2; ++mf) {
#pragma unroll
        for (int nf = 0; nf < 2; ++nf) {
            f32x4 a = mf ? (nf ? acc11 : acc10) : (nf ? acc01 : acc00);
            int col = colb + (nf << 4);
            float bs = b_xh[col] + b_hh[col];
#pragma unroll
            for (int j = 0; j < 4; ++j) {
                int row = rowb + (mf << 4) + j;
                float v = tanh_fast(a[j] + bs);
                h_next[(size_t)row * HIDD + col] = __float2bfloat16(v);
            }
        }
    }

    // Tail: store converted next x slice (loads were issued at kernel start).
    if (!last) {
        u16x8 o;
        o[0]=bf16b(cv0.x); o[1]=bf16b(cv0.y); o[2]=bf16b(cv0.z); o[3]=bf16b(cv0.w);
        o[4]=bf16b(cv1.x); o[5]=bf16b(cv1.y); o[6]=bf16b(cv1.z); o[7]=bf16b(cv1.w);
        *(u16x8*)(void*)(xs_next + (size_t)crow * INDIM + ci) = o;
    }
}

// ---------------------------------------------------------------------------
// out[b][c] = h_T[b] . Why[:,c] + b_y[c]   (fp32, one wave per batch row)
// ---------------------------------------------------------------------------
__global__ __launch_bounds__(64) void out_kernel(
    const __hip_bfloat16* __restrict__ h, const float* __restrict__ Why,
    const float* __restrict__ b_y, float* __restrict__ out)
{
    int b = blockIdx.x, lane = threadIdx.x;
    float acc[NCLS];
#pragma unroll
    for (int c = 0; c < NCLS; ++c) acc[c] = 0.f;
    for (int kk = 0; kk < 16; ++kk) {
        int k = (kk << 6) + lane;
        float hv = __bfloat162float(h[(size_t)b * HIDD + k]);
#pragma unroll
        for (int c = 0; c < NCLS; ++c) acc[c] += hv * Why[(size_t)k * NCLS + c];
    }
#pragma unroll
    for (int c = 0; c < NCLS; ++c) {
        float v = acc[c];
#pragma unroll
        for (int off = 32; off > 0; off >>= 1) v += __shfl_down(v, off);
        if (lane == 0) out[(size_t)b * NCLS + c] = v + b_y[c];
    }
}

// ---------------------------------------------------------------------------
extern "C" void kernel_launch(void* const* d_in, const int* in_sizes, int n_in,
                              void* d_out, int out_size, void* d_ws, size_t ws_size,
                              hipStream_t stream)
{
    const float* x    = (const float*)d_in[0];
    const float* Wxh  = (const float*)d_in[1];
    const float* b_xh = (const float*)d_in[2];
    const float* Whh  = (const float*)d_in[3];
    const float* b_hh = (const float*)d_in[4];
    const float* Why  = (const float*)d_in[5];
    const float* b_y  = (const float*)d_in[6];
    float* out = (float*)d_out;

    char* ws = (char*)d_ws;                       // 12 MB used
    __hip_bfloat16* WhhT_hi = (__hip_bfloat16*)(ws);
    __hip_bfloat16* WhhT_lo = (__hip_bfloat16*)(ws + (2u << 20));
    __hip_bfloat16* WxhT_hi = (__hip_bfloat16*)(ws + (4u << 20));
    __hip_bfloat16* WxhT_lo = (__hip_bfloat16*)(ws + (5u << 20));
    __hip_bfloat16* h0      = (__hip_bfloat16*)(ws + (6u << 20));
    __hip_bfloat16* h1      = (__hip_bfloat16*)(ws + (8u << 20));
    __hip_bfloat16* xs0     = (__hip_bfloat16*)(ws + (10u << 20));
    __hip_bfloat16* xs1     = (__hip_bfloat16*)(ws + (11u << 20));

    prep_kernel<<<384, 256, 0, stream>>>(Whh, Wxh, WhhT_hi, WhhT_lo, WxhT_hi, WxhT_lo);
    convx_kernel<<<256, 256, 0, stream>>>(x, xs0, 0);

    __hip_bfloat16* hp[2] = {h0, h1};
    __hip_bfloat16* xs[2] = {xs0, xs1};
    for (int t = 0; t < TT; ++t) {
        step_kernel<<<dim3(16, 16), 256, 0, stream>>>(
            hp[t & 1], hp[(t + 1) & 1], xs[t & 1], xs[(t + 1) & 1],
            WhhT_hi, WhhT_lo, WxhT_hi, WxhT_lo,
            x, b_xh, b_hh, t, (t == 0) ? 1 : 0, (t == TT - 1) ? 1 : 0);
    }
    out_kernel<<<1024, 64, 0, stream>>>(hp[0], Why, b_y, out);
}